// Round 13
// baseline (272.451 us; speedup 1.0000x reference)
//
#include <hip/hip_runtime.h>

#define LRELU(v) ((v) > 0.f ? (v) : 0.2f * (v))

typedef __attribute__((ext_vector_type(8))) short bf16x8;
typedef __attribute__((ext_vector_type(4))) float f32x4;

__device__ __forceinline__ ushort f2bf(float x) {
    union { float f; unsigned u; } v; v.f = x;
    return (ushort)((v.u + 0x7FFF + ((v.u >> 16) & 1)) >> 16);   // RNE
}
__device__ __forceinline__ float bf2f(ushort b) {
    union { float f; unsigned u; } v; v.u = ((unsigned)b) << 16;
    return v.f;
}

// ---------------- prep: both weight transpose-casts in one launch ----------------

__global__ void tcast2_k(const float* __restrict__ W1, ushort* __restrict__ w1t,
                         const float* __restrict__ W2, ushort* __restrict__ w2t) {
    int i = blockIdx.x * blockDim.x + threadIdx.x;
    if (i < 128 * 256) {
        int k = i >> 8, c = i & 255;
        w1t[c * 128 + k] = f2bf(W1[i]);
    } else if (i < 128 * 256 + 256 * 64) {
        int j = i - 128 * 256;
        int k = j >> 6, c = j & 63;
        w2t[c * 256 + k] = f2bf(W2[j]);
    }
}

// ---------------- MFMA GEMM1: h1[M,256] = f2bf(x[M,128]) @ W1, + attn dots ----------------
// w1t [256][128] staged in LDS (64KB), XOR-swizzled 16B chunks: col' = col ^ (row&7).

__global__ __launch_bounds__(256) void gemm1_mfma(
        const float* __restrict__ x, const ushort* __restrict__ w1t,
        const float* __restrict__ asrc, const float* __restrict__ adst,
        ushort* __restrict__ hb, float* __restrict__ os, float* __restrict__ od, int M) {
    __shared__ ushort wl[32768];
    const int tid = threadIdx.x;
#pragma unroll
    for (int it = 0; it < 16; ++it) {
        const int id = it * 256 + tid;
        const int row = id >> 4, col = id & 15;
        bf16x8 v = *(const bf16x8*)(w1t + (size_t)id * 8);
        *(bf16x8*)(wl + (((row << 4) | (col ^ (row & 7))) * 8)) = v;
    }
    __syncthreads();

    const int lane = tid & 63;
    const int c15 = lane & 15, rgrp = lane >> 4;
    const int row0 = blockIdx.x * 64 + (tid >> 6) * 16;
    int arow = row0 + c15; if (arow >= M) arow = M - 1;

    bf16x8 a[4];
#pragma unroll
    for (int ks = 0; ks < 4; ++ks) {
        const float* ap = x + (size_t)arow * 128 + ks * 32 + rgrp * 8;
        const float4 f0 = *(const float4*)ap;
        const float4 f1 = *(const float4*)(ap + 4);
        bf16x8 t;
        t[0] = (short)f2bf(f0.x); t[1] = (short)f2bf(f0.y);
        t[2] = (short)f2bf(f0.z); t[3] = (short)f2bf(f0.w);
        t[4] = (short)f2bf(f1.x); t[5] = (short)f2bf(f1.y);
        t[6] = (short)f2bf(f1.z); t[7] = (short)f2bf(f1.w);
        a[ks] = t;
    }

    f32x4 acc[16];
#pragma unroll
    for (int ct = 0; ct < 16; ++ct) acc[ct] = (f32x4){0.f, 0.f, 0.f, 0.f};

#pragma unroll
    for (int ct = 0; ct < 16; ++ct) {
        const int r = ct * 16 + c15;
#pragma unroll
        for (int ks = 0; ks < 4; ++ks) {
            const int chunk = (r << 4) | ((ks * 4 + rgrp) ^ (r & 7));
            bf16x8 b = *(const bf16x8*)(wl + chunk * 8);
            acc[ct] = __builtin_amdgcn_mfma_f32_16x16x32_bf16(a[ks], b, acc[ct], 0, 0, 0);
        }
    }

#pragma unroll
    for (int ct = 0; ct < 16; ++ct) {
        const int col = ct * 16 + c15;
#pragma unroll
        for (int r = 0; r < 4; ++r) {
            const int row = row0 + rgrp * 4 + r;
            if (row < M) hb[(size_t)row * 256 + col] = f2bf(acc[ct][r]);
        }
    }

#pragma unroll
    for (int hd = 0; hd < 4; ++hd) {
        float sv[4] = {0.f, 0.f, 0.f, 0.f}, dv[4] = {0.f, 0.f, 0.f, 0.f};
#pragma unroll
        for (int j = 0; j < 4; ++j) {
            const int ct = hd * 4 + j;
            const float ws = asrc[ct * 16 + c15], wd = adst[ct * 16 + c15];
#pragma unroll
            for (int r = 0; r < 4; ++r) { sv[r] += acc[ct][r] * ws; dv[r] += acc[ct][r] * wd; }
        }
#pragma unroll
        for (int r = 0; r < 4; ++r) {
#pragma unroll
            for (int m = 1; m < 16; m <<= 1) {
                sv[r] += __shfl_xor(sv[r], m); dv[r] += __shfl_xor(dv[r], m);
            }
        }
        if (c15 == 0) {
#pragma unroll
            for (int r = 0; r < 4; ++r) {
                const int row = row0 + rgrp * 4 + r;
                if (row < M) { os[row * 4 + hd] = sv[r]; od[row * 4 + hd] = dv[r]; }
            }
        }
    }
}

// ---------------- MFMA GEMM2: h2[M,64] = aggb[M,256] @ W2, + attn dots ----------------

__global__ __launch_bounds__(256) void gemm2_mfma(
        const ushort* __restrict__ ab, const ushort* __restrict__ w2t,
        const float* __restrict__ asrc, const float* __restrict__ adst,
        ushort* __restrict__ hb, float* __restrict__ os, float* __restrict__ od, int M) {
    __shared__ ushort wl[16384];
    const int tid = threadIdx.x;
#pragma unroll
    for (int it = 0; it < 8; ++it) {
        const int id = it * 256 + tid;
        const int row = id >> 5, col = id & 31;
        bf16x8 v = *(const bf16x8*)(w2t + (size_t)id * 8);
        *(bf16x8*)(wl + (((row << 5) | (col ^ (row & 7))) * 8)) = v;
    }
    __syncthreads();

    const int lane = tid & 63;
    const int c15 = lane & 15, rgrp = lane >> 4;
    const int row0 = blockIdx.x * 64 + (tid >> 6) * 16;

    bf16x8 a[8];
#pragma unroll
    for (int ks = 0; ks < 8; ++ks)
        a[ks] = *(const bf16x8*)(ab + (size_t)(row0 + c15) * 256 + ks * 32 + rgrp * 8);

    f32x4 acc[4];
#pragma unroll
    for (int ct = 0; ct < 4; ++ct) acc[ct] = (f32x4){0.f, 0.f, 0.f, 0.f};

#pragma unroll
    for (int ct = 0; ct < 4; ++ct) {
        const int r = ct * 16 + c15;
#pragma unroll
        for (int ks = 0; ks < 8; ++ks) {
            const int chunk = (r << 5) | ((ks * 4 + rgrp) ^ (r & 7));
            bf16x8 b = *(const bf16x8*)(wl + chunk * 8);
            acc[ct] = __builtin_amdgcn_mfma_f32_16x16x32_bf16(a[ks], b, acc[ct], 0, 0, 0);
        }
    }

#pragma unroll
    for (int ct = 0; ct < 4; ++ct) {
        const int col = ct * 16 + c15;
#pragma unroll
        for (int r = 0; r < 4; ++r) {
            const int row = row0 + rgrp * 4 + r;
            if (row < M) hb[(size_t)row * 64 + col] = f2bf(acc[ct][r]);
        }
    }

    float sv[4] = {0.f, 0.f, 0.f, 0.f}, dv[4] = {0.f, 0.f, 0.f, 0.f};
#pragma unroll
    for (int ct = 0; ct < 4; ++ct) {
        const float ws = asrc[ct * 16 + c15], wd = adst[ct * 16 + c15];
#pragma unroll
        for (int r = 0; r < 4; ++r) { sv[r] += acc[ct][r] * ws; dv[r] += acc[ct][r] * wd; }
    }
#pragma unroll
    for (int r = 0; r < 4; ++r) {
#pragma unroll
        for (int m = 1; m < 16; m <<= 1) {
            sv[r] += __shfl_xor(sv[r], m); dv[r] += __shfl_xor(dv[r], m);
        }
    }
    if (c15 == 0) {
#pragma unroll
        for (int r = 0; r < 4; ++r) {
            const int row = row0 + rgrp * 4 + r;
            if (row < M) { os[row] = sv[r]; od[row] = dv[r]; }
        }
    }
}

// ---------------- unified CSR: rank / scan / per-layer place+pal ----------------
// cnt8: 8 planes x 2N; plane = (t>>10)&7 over the COMBINED edge index t.

__global__ void rank_all_k(const int* __restrict__ ei1, int E1,
                           const int* __restrict__ ei2, int E2, int N,
                           int* __restrict__ cnt8, int* __restrict__ rnk) {
    const int base = blockIdx.x * 1024;
    int* __restrict__ c = cnt8 + (size_t)(blockIdx.x & 7) * 2 * N;
#pragma unroll
    for (int j = 0; j < 4; ++j) {
        const int t = base + j * 256 + threadIdx.x;
        if (t < E1)            rnk[t] = atomicAdd(&c[ei1[E1 + t]], 1);
        else if (t < E1 + E2)  rnk[t] = atomicAdd(&c[N + ei2[E2 + (t - E1)]], 1);
    }
}

__global__ void scan1_k(const int* __restrict__ cnt8, int* __restrict__ cnt_tot,
                        int* __restrict__ off, int* __restrict__ bsum, int NN) {
    __shared__ int tmp[256];
    const int i = blockIdx.x * 256 + threadIdx.x;
    int v = 0;
    if (i < NN) {
#pragma unroll
        for (int r = 0; r < 8; ++r) v += cnt8[(size_t)r * NN + i];
        cnt_tot[i] = v;
    }
    tmp[threadIdx.x] = v;
    __syncthreads();
#pragma unroll
    for (int d = 1; d < 256; d <<= 1) {
        int t = (threadIdx.x >= d) ? tmp[threadIdx.x - d] : 0;
        __syncthreads();
        tmp[threadIdx.x] += t;
        __syncthreads();
    }
    if (i < NN) off[i] = tmp[threadIdx.x] - v;
    if (threadIdx.x == 255) bsum[blockIdx.x] = tmp[255];
}

__global__ void scan23_k(int* __restrict__ off, const int* __restrict__ bsum,
                         int* __restrict__ cnt8, int NN) {
    const int b = blockIdx.x;
    int pre = 0;
    for (int i = (threadIdx.x & 63); i < b; i += 64) pre += bsum[i];
#pragma unroll
    for (int m = 1; m < 64; m <<= 1) pre += __shfl_xor(pre, m);
    const int i = b * 256 + threadIdx.x;
    if (i < NN) {
        int run = off[i] + pre;
        off[i] = run;
#pragma unroll
        for (int r = 0; r < 8; ++r) {
            const int c = cnt8[(size_t)r * NN + i];
            cnt8[(size_t)r * NN + i] = run;
            run += c;
        }
    }
}

// place + inline alpha, layer 1 (H=4): writes src (4B) + pal float4
__global__ void place1pal_k(const int* __restrict__ ei, int E, int N,
                            const int* __restrict__ base8, const int* __restrict__ rnk,
                            const float* __restrict__ as, const float* __restrict__ ad,
                            int* __restrict__ src, float* __restrict__ pal) {
    const int base = blockIdx.x * 1024;
#pragma unroll
    for (int j = 0; j < 4; ++j) {
        const int t = base + j * 256 + threadIdx.x;
        if (t >= E) continue;
        const int s = ei[t], d = ei[E + t];
        const int slot = base8[(size_t)((t >> 10) & 7) * 2 * N + d] + rnk[t];
        src[slot] = s;
        const float4 av = *(const float4*)(as + (size_t)s * 4);
        const float4 dv = *(const float4*)(ad + (size_t)d * 4);
        float4 p;
        p.x = __expf(LRELU(av.x + dv.x));
        p.y = __expf(LRELU(av.y + dv.y));
        p.z = __expf(LRELU(av.z + dv.z));
        p.w = __expf(LRELU(av.w + dv.w));
        ((float4*)pal)[slot] = p;
    }
}

// place + inline alpha, layer 2 (H=1): combined index t = E1 + e; slot local to layer 2
__global__ void place2pal_k(const int* __restrict__ ei, int E, int N, int E1,
                            const int* __restrict__ base8, const int* __restrict__ rnk,
                            const float* __restrict__ as, const float* __restrict__ ad,
                            int* __restrict__ src, float* __restrict__ pal) {
    const int base = blockIdx.x * 1024;
#pragma unroll
    for (int j = 0; j < 4; ++j) {
        const int e = base + j * 256 + threadIdx.x;
        if (e >= E) continue;
        const int t = E1 + e;
        const int s = ei[e], d = ei[E + e];
        const int slot = base8[(size_t)((t >> 10) & 7) * 2 * N + N + d] + rnk[t];
        src[slot] = s;
        pal[slot - E1] = __expf(LRELU(as[s] + ad[d]));
    }
}

// ---------------- pull layer 1: one wave per node, 16/8/4/1-edge batch tiers ----------------

__global__ __launch_bounds__(256) void pull1_k(
        const int* __restrict__ off, const int* __restrict__ cnt,
        const int* __restrict__ src, const float* __restrict__ pal,
        const ushort* __restrict__ hb,
        const float* __restrict__ as, const float* __restrict__ ad,
        const float* __restrict__ bias, ushort* __restrict__ aggb, int N) {
    const int n = blockIdx.x * 4 + (threadIdx.x >> 6);
    if (n >= N) return;
    const int lane = threadIdx.x & 63;
    const int hh = lane >> 4;
    const int start = off[n];
    const int end = start + cnt[n];
    float4 acc = {0.f, 0.f, 0.f, 0.f};
    float den = 0.f;
    int i = start;
    for (; i + 16 <= end; i += 16) {
        int ss[16]; float pp[16]; ushort4 hv[16];
#pragma unroll
        for (int j = 0; j < 16; ++j) {
            ss[j] = src[i + j];
            pp[j] = pal[(size_t)(i + j) * 4 + hh];
        }
#pragma unroll
        for (int j = 0; j < 16; ++j)
            hv[j] = *(const ushort4*)(hb + (size_t)ss[j] * 256 + lane * 4);
#pragma unroll
        for (int j = 0; j < 16; ++j) {
            den += pp[j];
            acc.x += pp[j] * bf2f(hv[j].x); acc.y += pp[j] * bf2f(hv[j].y);
            acc.z += pp[j] * bf2f(hv[j].z); acc.w += pp[j] * bf2f(hv[j].w);
        }
    }
    for (; i + 8 <= end; i += 8) {
        int ss[8]; float pp[8]; ushort4 hv[8];
#pragma unroll
        for (int j = 0; j < 8; ++j) {
            ss[j] = src[i + j];
            pp[j] = pal[(size_t)(i + j) * 4 + hh];
        }
#pragma unroll
        for (int j = 0; j < 8; ++j)
            hv[j] = *(const ushort4*)(hb + (size_t)ss[j] * 256 + lane * 4);
#pragma unroll
        for (int j = 0; j < 8; ++j) {
            den += pp[j];
            acc.x += pp[j] * bf2f(hv[j].x); acc.y += pp[j] * bf2f(hv[j].y);
            acc.z += pp[j] * bf2f(hv[j].z); acc.w += pp[j] * bf2f(hv[j].w);
        }
    }
    for (; i + 4 <= end; i += 4) {
        int ss[4]; float pp[4]; ushort4 hv[4];
#pragma unroll
        for (int j = 0; j < 4; ++j) {
            ss[j] = src[i + j];
            pp[j] = pal[(size_t)(i + j) * 4 + hh];
        }
#pragma unroll
        for (int j = 0; j < 4; ++j)
            hv[j] = *(const ushort4*)(hb + (size_t)ss[j] * 256 + lane * 4);
#pragma unroll
        for (int j = 0; j < 4; ++j) {
            den += pp[j];
            acc.x += pp[j] * bf2f(hv[j].x); acc.y += pp[j] * bf2f(hv[j].y);
            acc.z += pp[j] * bf2f(hv[j].z); acc.w += pp[j] * bf2f(hv[j].w);
        }
    }
    for (; i < end; ++i) {
        const int s = src[i];
        const float p = pal[(size_t)i * 4 + hh];
        const ushort4 hv = *(const ushort4*)(hb + (size_t)s * 256 + lane * 4);
        den += p;
        acc.x += p * bf2f(hv.x); acc.y += p * bf2f(hv.y);
        acc.z += p * bf2f(hv.z); acc.w += p * bf2f(hv.w);
    }
    {   // self-loop
        const float p = __expf(LRELU(as[n * 4 + hh] + ad[n * 4 + hh]));
        const ushort4 hv = *(const ushort4*)(hb + (size_t)n * 256 + lane * 4);
        den += p;
        acc.x += p * bf2f(hv.x); acc.y += p * bf2f(hv.y);
        acc.z += p * bf2f(hv.z); acc.w += p * bf2f(hv.w);
    }
    const float rden = 1.f / den;
    const float4 bv = *(const float4*)(bias + lane * 4);
    ushort4 o;
    o.x = f2bf(fmaxf(acc.x * rden + bv.x, 0.f));
    o.y = f2bf(fmaxf(acc.y * rden + bv.y, 0.f));
    o.z = f2bf(fmaxf(acc.z * rden + bv.z, 0.f));
    o.w = f2bf(fmaxf(acc.w * rden + bv.w, 0.f));
    *(ushort4*)(aggb + (size_t)n * 256 + lane * 4) = o;
}

// ---------------- pull layer 2: fused bias + L2 norm, writes d_out ----------------

__global__ __launch_bounds__(256) void pull2_k(
        const int* __restrict__ off, const int* __restrict__ cnt,
        const int* __restrict__ src, const float* __restrict__ pal,
        const ushort* __restrict__ hb,
        const float* __restrict__ as, const float* __restrict__ ad,
        const float* __restrict__ bias, float* __restrict__ out, int N, int E1) {
    const int n = blockIdx.x * 4 + (threadIdx.x >> 6);
    if (n >= N) return;
    const int lane = threadIdx.x & 63;
    const int g = lane >> 4;
    const int q = lane & 15;
    const int start = off[N + n] - E1;
    const int end = start + cnt[N + n];
    float4 acc = {0.f, 0.f, 0.f, 0.f};
    float den = 0.f;
    int base = start;
    for (; base + 16 <= end; base += 16) {
        int s[4]; float p[4]; ushort4 h[4];
#pragma unroll
        for (int j = 0; j < 4; ++j) { const int idx = base + j * 4 + g; s[j] = src[idx]; p[j] = pal[idx]; }
#pragma unroll
        for (int j = 0; j < 4; ++j) h[j] = *(const ushort4*)(hb + (size_t)s[j] * 64 + q * 4);
#pragma unroll
        for (int j = 0; j < 4; ++j) {
            den += p[j];
            acc.x += p[j] * bf2f(h[j].x); acc.y += p[j] * bf2f(h[j].y);
            acc.z += p[j] * bf2f(h[j].z); acc.w += p[j] * bf2f(h[j].w);
        }
    }
    for (; base + 8 <= end; base += 8) {
        const int i0 = base + g, i1 = base + 4 + g;
        const int s0 = src[i0], s1 = src[i1];
        const float p0 = pal[i0], p1 = pal[i1];
        const ushort4 h0 = *(const ushort4*)(hb + (size_t)s0 * 64 + q * 4);
        const ushort4 h1 = *(const ushort4*)(hb + (size_t)s1 * 64 + q * 4);
        den += p0 + p1;
        acc.x += p0 * bf2f(h0.x) + p1 * bf2f(h1.x);
        acc.y += p0 * bf2f(h0.y) + p1 * bf2f(h1.y);
        acc.z += p0 * bf2f(h0.z) + p1 * bf2f(h1.z);
        acc.w += p0 * bf2f(h0.w) + p1 * bf2f(h1.w);
    }
    for (; base < end; base += 4) {
        const int idx = base + g;
        const bool valid = idx < end;
        const int s = valid ? src[idx] : n;
        const float p = valid ? pal[idx] : 0.f;
        const ushort4 hv = *(const ushort4*)(hb + (size_t)s * 64 + q * 4);
        den += p;
        acc.x += p * bf2f(hv.x); acc.y += p * bf2f(hv.y);
        acc.z += p * bf2f(hv.z); acc.w += p * bf2f(hv.w);
    }
    if (g == 0) {   // self-loop counted once
        const float p = __expf(LRELU(as[n] + ad[n]));
        const ushort4 hv = *(const ushort4*)(hb + (size_t)n * 64 + q * 4);
        den += p;
        acc.x += p * bf2f(hv.x); acc.y += p * bf2f(hv.y);
        acc.z += p * bf2f(hv.z); acc.w += p * bf2f(hv.w);
    }
#pragma unroll
    for (int m = 16; m < 64; m <<= 1) {
        acc.x += __shfl_xor(acc.x, m); acc.y += __shfl_xor(acc.y, m);
        acc.z += __shfl_xor(acc.z, m); acc.w += __shfl_xor(acc.w, m);
        den   += __shfl_xor(den, m);
    }
    const float rden = 1.f / den;
    const float4 bv = *(const float4*)(bias + q * 4);
    float4 v;
    v.x = acc.x * rden + bv.x; v.y = acc.y * rden + bv.y;
    v.z = acc.z * rden + bv.z; v.w = acc.w * rden + bv.w;
    float ss2 = v.x * v.x + v.y * v.y + v.z * v.z + v.w * v.w;
#pragma unroll
    for (int m = 1; m < 16; m <<= 1) ss2 += __shfl_xor(ss2, m);
    const float rn = 1.f / fmaxf(sqrtf(ss2), 1e-12f);
    if (g == 0) {
        float4 o; o.x = v.x * rn; o.y = v.y * rn; o.z = v.z * rn; o.w = v.w * rn;
        *(float4*)(out + (size_t)n * 64 + q * 4) = o;
    }
}

// ---------------- launch ----------------

extern "C" void kernel_launch(void* const* d_in, const int* in_sizes, int n_in,
                              void* d_out, int out_size, void* d_ws, size_t ws_size,
                              hipStream_t stream) {
    const float* x   = (const float*)d_in[0];
    const int*   ei1 = (const int*)d_in[1];
    const int*   ei2 = (const int*)d_in[2];
    const float* W1  = (const float*)d_in[3];
    const float* as1 = (const float*)d_in[4];
    const float* ad1 = (const float*)d_in[5];
    const float* b1  = (const float*)d_in[6];
    const float* W2  = (const float*)d_in[7];
    const float* as2 = (const float*)d_in[8];
    const float* ad2 = (const float*)d_in[9];
    const float* b2  = (const float*)d_in[10];

    const int N  = in_sizes[0] / 128;
    const int E1 = in_sizes[1] / 2;
    const int E2 = in_sizes[2] / 2;
    const int Etot = E1 + E2;
    const int NN = 2 * N;

    // ws layout (~95 MB; 106.4 MB proven available)
    ushort* h1b   = (ushort*)d_ws;                      // N*256 bf16
    ushort* agg1b = h1b + (size_t)N * 256;              // N*256 bf16
    ushort* h2b   = agg1b + (size_t)N * 256;            // N*64  bf16
    ushort* w1t   = h2b + (size_t)N * 64;               // 256*128
    ushort* w2t   = w1t + 256 * 128;                    // 64*256
    float*  pal1  = (float*)(w2t + 64 * 256);           // E1*4
    float*  pal2  = pal1 + (size_t)E1 * 4;              // E2
    int*    src   = (int*)(pal2 + E2);                  // Etot (L1 slots [0,E1), L2 [E1,Etot))
    int*    rnk   = src + Etot;                         // Etot
    int*    cnt8  = rnk + Etot;                         // 8 * 2N (becomes base8)
    int*    off   = cnt8 + (size_t)8 * NN;              // 2N
    int*    cntt  = off + NN;                           // 2N
    int*    bsum  = cntt + NN;                          // 512
    float*  s1    = (float*)(bsum + 512);               // N*4
    float*  d1v   = s1 + (size_t)N * 4;                 // N*4
    float*  s2    = d1v + (size_t)N * 4;                // N
    float*  d2v   = s2 + N;                             // N
    float*  out   = (float*)d_out;

    const int nb   = (NN + 255) / 256;
    const int eb4  = (Etot + 1023) / 1024;
    const int eb1  = (E1 + 1023) / 1024;
    const int eb2  = (E2 + 1023) / 1024;
    const int gblk = (N + 63) / 64;

    // prep
    tcast2_k<<<(128 * 256 + 256 * 64 + 255) / 256, 256, 0, stream>>>(W1, w1t, W2, w2t);
    hipMemsetAsync(cnt8, 0, (size_t)8 * NN * sizeof(int), stream);

    // unified CSR rank + scan
    rank_all_k<<<eb4, 256, 0, stream>>>(ei1, E1, ei2, E2, N, cnt8, rnk);
    scan1_k<<<nb, 256, 0, stream>>>(cnt8, cntt, off, bsum, NN);
    scan23_k<<<nb, 256, 0, stream>>>(off, bsum, cnt8, NN);

    // ---- layer 1 ----
    gemm1_mfma<<<gblk, 256, 0, stream>>>(x, w1t, as1, ad1, h1b, s1, d1v, N);
    place1pal_k<<<eb1, 256, 0, stream>>>(ei1, E1, N, cnt8, rnk, s1, d1v, src, pal1);
    pull1_k<<<(N + 3) / 4, 256, 0, stream>>>(off, cntt, src, pal1, h1b, s1, d1v, b1, agg1b, N);

    // ---- layer 2 ----
    gemm2_mfma<<<gblk, 256, 0, stream>>>(agg1b, w2t, as2, ad2, h2b, s2, d2v, N);
    place2pal_k<<<eb2, 256, 0, stream>>>(ei2, E2, N, E1, cnt8, rnk, s2, d2v, src, pal2);
    pull2_k<<<(N + 3) / 4, 256, 0, stream>>>(off, cntt, src + E1, pal2, h2b, s2, d2v, b2, out, N, E1);
}

// Round 14
// 264.497 us; speedup vs baseline: 1.0301x; 1.0301x over previous
//
#include <hip/hip_runtime.h>

#define LRELU(v) ((v) > 0.f ? (v) : 0.2f * (v))

typedef __attribute__((ext_vector_type(8))) short bf16x8;
typedef __attribute__((ext_vector_type(4))) float f32x4;

__device__ __forceinline__ ushort f2bf(float x) {
    union { float f; unsigned u; } v; v.f = x;
    return (ushort)((v.u + 0x7FFF + ((v.u >> 16) & 1)) >> 16);   // RNE
}
__device__ __forceinline__ float bf2f(ushort b) {
    union { float f; unsigned u; } v; v.u = ((unsigned)b) << 16;
    return v.f;
}

// ---------------- prep: both weight transpose-casts in one launch ----------------

__global__ void tcast2_k(const float* __restrict__ W1, ushort* __restrict__ w1t,
                         const float* __restrict__ W2, ushort* __restrict__ w2t) {
    int i = blockIdx.x * blockDim.x + threadIdx.x;
    if (i < 128 * 256) {
        int k = i >> 8, c = i & 255;
        w1t[c * 128 + k] = f2bf(W1[i]);
    } else if (i < 128 * 256 + 256 * 64) {
        int j = i - 128 * 256;
        int k = j >> 6, c = j & 63;
        w2t[c * 256 + k] = f2bf(W2[j]);
    }
}

// ---------------- MFMA GEMM1: h1[M,256] = f2bf(x[M,128]) @ W1, + attn dots ----------------
// w1t [256][128] staged in LDS (64KB), XOR-swizzled 16B chunks: col' = col ^ (row&7).

__global__ __launch_bounds__(256) void gemm1_mfma(
        const float* __restrict__ x, const ushort* __restrict__ w1t,
        const float* __restrict__ asrc, const float* __restrict__ adst,
        ushort* __restrict__ hb, float* __restrict__ os, float* __restrict__ od, int M) {
    __shared__ ushort wl[32768];
    const int tid = threadIdx.x;
#pragma unroll
    for (int it = 0; it < 16; ++it) {
        const int id = it * 256 + tid;
        const int row = id >> 4, col = id & 15;
        bf16x8 v = *(const bf16x8*)(w1t + (size_t)id * 8);
        *(bf16x8*)(wl + (((row << 4) | (col ^ (row & 7))) * 8)) = v;
    }
    __syncthreads();

    const int lane = tid & 63;
    const int c15 = lane & 15, rgrp = lane >> 4;
    const int row0 = blockIdx.x * 64 + (tid >> 6) * 16;
    int arow = row0 + c15; if (arow >= M) arow = M - 1;

    bf16x8 a[4];
#pragma unroll
    for (int ks = 0; ks < 4; ++ks) {
        const float* ap = x + (size_t)arow * 128 + ks * 32 + rgrp * 8;
        const float4 f0 = *(const float4*)ap;
        const float4 f1 = *(const float4*)(ap + 4);
        bf16x8 t;
        t[0] = (short)f2bf(f0.x); t[1] = (short)f2bf(f0.y);
        t[2] = (short)f2bf(f0.z); t[3] = (short)f2bf(f0.w);
        t[4] = (short)f2bf(f1.x); t[5] = (short)f2bf(f1.y);
        t[6] = (short)f2bf(f1.z); t[7] = (short)f2bf(f1.w);
        a[ks] = t;
    }

    f32x4 acc[16];
#pragma unroll
    for (int ct = 0; ct < 16; ++ct) acc[ct] = (f32x4){0.f, 0.f, 0.f, 0.f};

#pragma unroll
    for (int ct = 0; ct < 16; ++ct) {
        const int r = ct * 16 + c15;
#pragma unroll
        for (int ks = 0; ks < 4; ++ks) {
            const int chunk = (r << 4) | ((ks * 4 + rgrp) ^ (r & 7));
            bf16x8 b = *(const bf16x8*)(wl + chunk * 8);
            acc[ct] = __builtin_amdgcn_mfma_f32_16x16x32_bf16(a[ks], b, acc[ct], 0, 0, 0);
        }
    }

#pragma unroll
    for (int ct = 0; ct < 16; ++ct) {
        const int col = ct * 16 + c15;
#pragma unroll
        for (int r = 0; r < 4; ++r) {
            const int row = row0 + rgrp * 4 + r;
            if (row < M) hb[(size_t)row * 256 + col] = f2bf(acc[ct][r]);
        }
    }

#pragma unroll
    for (int hd = 0; hd < 4; ++hd) {
        float sv[4] = {0.f, 0.f, 0.f, 0.f}, dv[4] = {0.f, 0.f, 0.f, 0.f};
#pragma unroll
        for (int j = 0; j < 4; ++j) {
            const int ct = hd * 4 + j;
            const float ws = asrc[ct * 16 + c15], wd = adst[ct * 16 + c15];
#pragma unroll
            for (int r = 0; r < 4; ++r) { sv[r] += acc[ct][r] * ws; dv[r] += acc[ct][r] * wd; }
        }
#pragma unroll
        for (int r = 0; r < 4; ++r) {
#pragma unroll
            for (int m = 1; m < 16; m <<= 1) {
                sv[r] += __shfl_xor(sv[r], m); dv[r] += __shfl_xor(dv[r], m);
            }
        }
        if (c15 == 0) {
#pragma unroll
            for (int r = 0; r < 4; ++r) {
                const int row = row0 + rgrp * 4 + r;
                if (row < M) { os[row * 4 + hd] = sv[r]; od[row * 4 + hd] = dv[r]; }
            }
        }
    }
}

// ---------------- MFMA GEMM2: h2[M,64] = aggb[M,256] @ W2, + attn dots ----------------

__global__ __launch_bounds__(256) void gemm2_mfma(
        const ushort* __restrict__ ab, const ushort* __restrict__ w2t,
        const float* __restrict__ asrc, const float* __restrict__ adst,
        ushort* __restrict__ hb, float* __restrict__ os, float* __restrict__ od, int M) {
    __shared__ ushort wl[16384];
    const int tid = threadIdx.x;
#pragma unroll
    for (int it = 0; it < 8; ++it) {
        const int id = it * 256 + tid;
        const int row = id >> 5, col = id & 31;
        bf16x8 v = *(const bf16x8*)(w2t + (size_t)id * 8);
        *(bf16x8*)(wl + (((row << 5) | (col ^ (row & 7))) * 8)) = v;
    }
    __syncthreads();

    const int lane = tid & 63;
    const int c15 = lane & 15, rgrp = lane >> 4;
    const int row0 = blockIdx.x * 64 + (tid >> 6) * 16;

    bf16x8 a[8];
#pragma unroll
    for (int ks = 0; ks < 8; ++ks)
        a[ks] = *(const bf16x8*)(ab + (size_t)(row0 + c15) * 256 + ks * 32 + rgrp * 8);

    f32x4 acc[4];
#pragma unroll
    for (int ct = 0; ct < 4; ++ct) acc[ct] = (f32x4){0.f, 0.f, 0.f, 0.f};

#pragma unroll
    for (int ct = 0; ct < 4; ++ct) {
        const int r = ct * 16 + c15;
#pragma unroll
        for (int ks = 0; ks < 8; ++ks) {
            const int chunk = (r << 5) | ((ks * 4 + rgrp) ^ (r & 7));
            bf16x8 b = *(const bf16x8*)(wl + chunk * 8);
            acc[ct] = __builtin_amdgcn_mfma_f32_16x16x32_bf16(a[ks], b, acc[ct], 0, 0, 0);
        }
    }

#pragma unroll
    for (int ct = 0; ct < 4; ++ct) {
        const int col = ct * 16 + c15;
#pragma unroll
        for (int r = 0; r < 4; ++r) {
            const int row = row0 + rgrp * 4 + r;
            if (row < M) hb[(size_t)row * 64 + col] = f2bf(acc[ct][r]);
        }
    }

    float sv[4] = {0.f, 0.f, 0.f, 0.f}, dv[4] = {0.f, 0.f, 0.f, 0.f};
#pragma unroll
    for (int ct = 0; ct < 4; ++ct) {
        const float ws = asrc[ct * 16 + c15], wd = adst[ct * 16 + c15];
#pragma unroll
        for (int r = 0; r < 4; ++r) { sv[r] += acc[ct][r] * ws; dv[r] += acc[ct][r] * wd; }
    }
#pragma unroll
    for (int r = 0; r < 4; ++r) {
#pragma unroll
        for (int m = 1; m < 16; m <<= 1) {
            sv[r] += __shfl_xor(sv[r], m); dv[r] += __shfl_xor(dv[r], m);
        }
    }
    if (c15 == 0) {
#pragma unroll
        for (int r = 0; r < 4; ++r) {
            const int row = row0 + rgrp * 4 + r;
            if (row < M) { os[row] = sv[r]; od[row] = dv[r]; }
        }
    }
}

// ---------------- unified CSR: rank / scan / per-layer place+pal ----------------
// cnt8: 8 planes x 2N; plane = blockIdx&7 == (t>>10)&7 over combined index t.

__global__ void rank_all_k(const int* __restrict__ ei1, int E1,
                           const int* __restrict__ ei2, int E2, int N,
                           int* __restrict__ cnt8, int* __restrict__ rnk) {
    const int base = blockIdx.x * 1024;
    int* __restrict__ c = cnt8 + (size_t)(blockIdx.x & 7) * 2 * N;
#pragma unroll
    for (int j = 0; j < 4; ++j) {
        const int t = base + j * 256 + threadIdx.x;
        if (t < E1)            rnk[t] = atomicAdd(&c[ei1[E1 + t]], 1);
        else if (t < E1 + E2)  rnk[t] = atomicAdd(&c[N + ei2[E2 + (t - E1)]], 1);
    }
}

__global__ void scan1_k(const int* __restrict__ cnt8, int* __restrict__ cnt_tot,
                        int* __restrict__ off, int* __restrict__ bsum, int NN) {
    __shared__ int tmp[256];
    const int i = blockIdx.x * 256 + threadIdx.x;
    int v = 0;
    if (i < NN) {
#pragma unroll
        for (int r = 0; r < 8; ++r) v += cnt8[(size_t)r * NN + i];
        cnt_tot[i] = v;
    }
    tmp[threadIdx.x] = v;
    __syncthreads();
#pragma unroll
    for (int d = 1; d < 256; d <<= 1) {
        int t = (threadIdx.x >= d) ? tmp[threadIdx.x - d] : 0;
        __syncthreads();
        tmp[threadIdx.x] += t;
        __syncthreads();
    }
    if (i < NN) off[i] = tmp[threadIdx.x] - v;
    if (threadIdx.x == 255) bsum[blockIdx.x] = tmp[255];
}

__global__ void scan23_k(int* __restrict__ off, const int* __restrict__ bsum,
                         int* __restrict__ cnt8, int NN) {
    const int b = blockIdx.x;
    int pre = 0;
    for (int i = (threadIdx.x & 63); i < b; i += 64) pre += bsum[i];
#pragma unroll
    for (int m = 1; m < 64; m <<= 1) pre += __shfl_xor(pre, m);
    const int i = b * 256 + threadIdx.x;
    if (i < NN) {
        int run = off[i] + pre;
        off[i] = run;
#pragma unroll
        for (int r = 0; r < 8; ++r) {
            const int c = cnt8[(size_t)r * NN + i];
            cnt8[(size_t)r * NN + i] = run;
            run += c;
        }
    }
}

// place + inline alpha, layer 1 (H=4): writes src (4B) + pal float4
__global__ void place1pal_k(const int* __restrict__ ei, int E, int N,
                            const int* __restrict__ base8, const int* __restrict__ rnk,
                            const float* __restrict__ as, const float* __restrict__ ad,
                            int* __restrict__ src, float* __restrict__ pal) {
    const int base = blockIdx.x * 1024;
#pragma unroll
    for (int j = 0; j < 4; ++j) {
        const int t = base + j * 256 + threadIdx.x;
        if (t >= E) continue;
        const int s = ei[t], d = ei[E + t];
        const int slot = base8[(size_t)((t >> 10) & 7) * 2 * N + d] + rnk[t];
        src[slot] = s;
        const float4 av = *(const float4*)(as + (size_t)s * 4);
        const float4 dv = *(const float4*)(ad + (size_t)d * 4);
        float4 p;
        p.x = __expf(LRELU(av.x + dv.x));
        p.y = __expf(LRELU(av.y + dv.y));
        p.z = __expf(LRELU(av.z + dv.z));
        p.w = __expf(LRELU(av.w + dv.w));
        ((float4*)pal)[slot] = p;
    }
}

// place + inline alpha, layer 2 (H=1): combined index t = E1 + e; slot local to layer 2
__global__ void place2pal_k(const int* __restrict__ ei, int E, int N, int E1,
                            const int* __restrict__ base8, const int* __restrict__ rnk,
                            const float* __restrict__ as, const float* __restrict__ ad,
                            int* __restrict__ src, float* __restrict__ pal) {
    const int base = blockIdx.x * 1024;
#pragma unroll
    for (int j = 0; j < 4; ++j) {
        const int e = base + j * 256 + threadIdx.x;
        if (e >= E) continue;
        const int t = E1 + e;
        const int s = ei[e], d = ei[E + e];
        const int slot = base8[(size_t)((t >> 10) & 7) * 2 * N + N + d] + rnk[t];
        src[slot] = s;
        pal[slot - E1] = __expf(LRELU(as[s] + ad[d]));
    }
}

// ---------------- pull layer 1: one wave per node, 8/4/1 tiers (r10 structure) ----------------

__global__ __launch_bounds__(256) void pull1_k(
        const int* __restrict__ off, const int* __restrict__ cnt,
        const int* __restrict__ src, const float* __restrict__ pal,
        const ushort* __restrict__ hb,
        const float* __restrict__ as, const float* __restrict__ ad,
        const float* __restrict__ bias, ushort* __restrict__ aggb, int N) {
    const int n = blockIdx.x * 4 + (threadIdx.x >> 6);
    if (n >= N) return;
    const int lane = threadIdx.x & 63;
    const int hh = lane >> 4;
    const int start = off[n];
    const int end = start + cnt[n];
    float4 acc = {0.f, 0.f, 0.f, 0.f};
    float den = 0.f;
    int i = start;
    for (; i + 8 <= end; i += 8) {
        int ss[8]; float pp[8]; ushort4 hv[8];
#pragma unroll
        for (int j = 0; j < 8; ++j) {
            ss[j] = src[i + j];
            pp[j] = pal[(size_t)(i + j) * 4 + hh];
        }
#pragma unroll
        for (int j = 0; j < 8; ++j)
            hv[j] = *(const ushort4*)(hb + (size_t)ss[j] * 256 + lane * 4);
#pragma unroll
        for (int j = 0; j < 8; ++j) {
            den += pp[j];
            acc.x += pp[j] * bf2f(hv[j].x); acc.y += pp[j] * bf2f(hv[j].y);
            acc.z += pp[j] * bf2f(hv[j].z); acc.w += pp[j] * bf2f(hv[j].w);
        }
    }
    for (; i + 4 <= end; i += 4) {
        int ss[4]; float pp[4]; ushort4 hv[4];
#pragma unroll
        for (int j = 0; j < 4; ++j) {
            ss[j] = src[i + j];
            pp[j] = pal[(size_t)(i + j) * 4 + hh];
        }
#pragma unroll
        for (int j = 0; j < 4; ++j)
            hv[j] = *(const ushort4*)(hb + (size_t)ss[j] * 256 + lane * 4);
#pragma unroll
        for (int j = 0; j < 4; ++j) {
            den += pp[j];
            acc.x += pp[j] * bf2f(hv[j].x); acc.y += pp[j] * bf2f(hv[j].y);
            acc.z += pp[j] * bf2f(hv[j].z); acc.w += pp[j] * bf2f(hv[j].w);
        }
    }
    for (; i < end; ++i) {
        const int s = src[i];
        const float p = pal[(size_t)i * 4 + hh];
        const ushort4 hv = *(const ushort4*)(hb + (size_t)s * 256 + lane * 4);
        den += p;
        acc.x += p * bf2f(hv.x); acc.y += p * bf2f(hv.y);
        acc.z += p * bf2f(hv.z); acc.w += p * bf2f(hv.w);
    }
    {   // self-loop
        const float p = __expf(LRELU(as[n * 4 + hh] + ad[n * 4 + hh]));
        const ushort4 hv = *(const ushort4*)(hb + (size_t)n * 256 + lane * 4);
        den += p;
        acc.x += p * bf2f(hv.x); acc.y += p * bf2f(hv.y);
        acc.z += p * bf2f(hv.z); acc.w += p * bf2f(hv.w);
    }
    const float rden = 1.f / den;
    const float4 bv = *(const float4*)(bias + lane * 4);
    ushort4 o;
    o.x = f2bf(fmaxf(acc.x * rden + bv.x, 0.f));
    o.y = f2bf(fmaxf(acc.y * rden + bv.y, 0.f));
    o.z = f2bf(fmaxf(acc.z * rden + bv.z, 0.f));
    o.w = f2bf(fmaxf(acc.w * rden + bv.w, 0.f));
    *(ushort4*)(aggb + (size_t)n * 256 + lane * 4) = o;
}

// ---------------- pull layer 2: r10 structure; fused bias + L2 norm ----------------

__global__ __launch_bounds__(256) void pull2_k(
        const int* __restrict__ off, const int* __restrict__ cnt,
        const int* __restrict__ src, const float* __restrict__ pal,
        const ushort* __restrict__ hb,
        const float* __restrict__ as, const float* __restrict__ ad,
        const float* __restrict__ bias, float* __restrict__ out, int N, int E1) {
    const int n = blockIdx.x * 4 + (threadIdx.x >> 6);
    if (n >= N) return;
    const int lane = threadIdx.x & 63;
    const int g = lane >> 4;
    const int q = lane & 15;
    const int start = off[N + n] - E1;
    const int end = start + cnt[N + n];
    float4 acc = {0.f, 0.f, 0.f, 0.f};
    float den = 0.f;
    int base = start;
    for (; base + 8 <= end; base += 8) {
        const int i0 = base + g, i1 = base + 4 + g;
        const int s0 = src[i0], s1 = src[i1];
        const float p0 = pal[i0], p1 = pal[i1];
        const ushort4 h0 = *(const ushort4*)(hb + (size_t)s0 * 64 + q * 4);
        const ushort4 h1 = *(const ushort4*)(hb + (size_t)s1 * 64 + q * 4);
        den += p0 + p1;
        acc.x += p0 * bf2f(h0.x) + p1 * bf2f(h1.x);
        acc.y += p0 * bf2f(h0.y) + p1 * bf2f(h1.y);
        acc.z += p0 * bf2f(h0.z) + p1 * bf2f(h1.z);
        acc.w += p0 * bf2f(h0.w) + p1 * bf2f(h1.w);
    }
    for (; base < end; base += 4) {
        const int idx = base + g;
        const bool valid = idx < end;
        const int s = valid ? src[idx] : n;
        const float p = valid ? pal[idx] : 0.f;
        const ushort4 hv = *(const ushort4*)(hb + (size_t)s * 64 + q * 4);
        den += p;
        acc.x += p * bf2f(hv.x); acc.y += p * bf2f(hv.y);
        acc.z += p * bf2f(hv.z); acc.w += p * bf2f(hv.w);
    }
    if (g == 0) {   // self-loop counted once
        const float p = __expf(LRELU(as[n] + ad[n]));
        const ushort4 hv = *(const ushort4*)(hb + (size_t)n * 64 + q * 4);
        den += p;
        acc.x += p * bf2f(hv.x); acc.y += p * bf2f(hv.y);
        acc.z += p * bf2f(hv.z); acc.w += p * bf2f(hv.w);
    }
#pragma unroll
    for (int m = 16; m < 64; m <<= 1) {
        acc.x += __shfl_xor(acc.x, m); acc.y += __shfl_xor(acc.y, m);
        acc.z += __shfl_xor(acc.z, m); acc.w += __shfl_xor(acc.w, m);
        den   += __shfl_xor(den, m);
    }
    const float rden = 1.f / den;
    const float4 bv = *(const float4*)(bias + q * 4);
    float4 v;
    v.x = acc.x * rden + bv.x; v.y = acc.y * rden + bv.y;
    v.z = acc.z * rden + bv.z; v.w = acc.w * rden + bv.w;
    float ss2 = v.x * v.x + v.y * v.y + v.z * v.z + v.w * v.w;
#pragma unroll
    for (int m = 1; m < 16; m <<= 1) ss2 += __shfl_xor(ss2, m);
    const float rn = 1.f / fmaxf(sqrtf(ss2), 1e-12f);
    if (g == 0) {
        float4 o; o.x = v.x * rn; o.y = v.y * rn; o.z = v.z * rn; o.w = v.w * rn;
        *(float4*)(out + (size_t)n * 64 + q * 4) = o;
    }
}

// ---------------- launch ----------------

extern "C" void kernel_launch(void* const* d_in, const int* in_sizes, int n_in,
                              void* d_out, int out_size, void* d_ws, size_t ws_size,
                              hipStream_t stream) {
    const float* x   = (const float*)d_in[0];
    const int*   ei1 = (const int*)d_in[1];
    const int*   ei2 = (const int*)d_in[2];
    const float* W1  = (const float*)d_in[3];
    const float* as1 = (const float*)d_in[4];
    const float* ad1 = (const float*)d_in[5];
    const float* b1  = (const float*)d_in[6];
    const float* W2  = (const float*)d_in[7];
    const float* as2 = (const float*)d_in[8];
    const float* ad2 = (const float*)d_in[9];
    const float* b2  = (const float*)d_in[10];

    const int N  = in_sizes[0] / 128;
    const int E1 = in_sizes[1] / 2;
    const int E2 = in_sizes[2] / 2;
    const int Etot = E1 + E2;
    const int NN = 2 * N;

    // ws layout (~95 MB; 106.4 MB proven available)
    ushort* h1b   = (ushort*)d_ws;                      // N*256 bf16
    ushort* agg1b = h1b + (size_t)N * 256;              // N*256 bf16
    ushort* h2b   = agg1b + (size_t)N * 256;            // N*64  bf16
    ushort* w1t   = h2b + (size_t)N * 64;               // 256*128
    ushort* w2t   = w1t + 256 * 128;                    // 64*256
    float*  pal1  = (float*)(w2t + 64 * 256);           // E1*4
    float*  pal2  = pal1 + (size_t)E1 * 4;              // E2
    int*    src   = (int*)(pal2 + E2);                  // Etot (L1 slots [0,E1), L2 [E1,Etot))
    int*    rnk   = src + Etot;                         // Etot
    int*    cnt8  = rnk + Etot;                         // 8 * 2N (becomes base8)
    int*    off   = cnt8 + (size_t)8 * NN;              // 2N
    int*    cntt  = off + NN;                           // 2N
    int*    bsum  = cntt + NN;                          // 512
    float*  s1    = (float*)(bsum + 512);               // N*4
    float*  d1v   = s1 + (size_t)N * 4;                 // N*4
    float*  s2    = d1v + (size_t)N * 4;                // N
    float*  d2v   = s2 + N;                             // N
    float*  out   = (float*)d_out;

    const int nb   = (NN + 255) / 256;
    const int eb4  = (Etot + 1023) / 1024;
    const int eb1  = (E1 + 1023) / 1024;
    const int eb2  = (E2 + 1023) / 1024;
    const int gblk = (N + 63) / 64;

    // prep
    tcast2_k<<<(128 * 256 + 256 * 64 + 255) / 256, 256, 0, stream>>>(W1, w1t, W2, w2t);
    hipMemsetAsync(cnt8, 0, (size_t)8 * NN * sizeof(int), stream);

    // unified CSR rank + scan
    rank_all_k<<<eb4, 256, 0, stream>>>(ei1, E1, ei2, E2, N, cnt8, rnk);
    scan1_k<<<nb, 256, 0, stream>>>(cnt8, cntt, off, bsum, NN);
    scan23_k<<<nb, 256, 0, stream>>>(off, bsum, cnt8, NN);

    // ---- layer 1 ----
    gemm1_mfma<<<gblk, 256, 0, stream>>>(x, w1t, as1, ad1, h1b, s1, d1v, N);
    place1pal_k<<<eb1, 256, 0, stream>>>(ei1, E1, N, cnt8, rnk, s1, d1v, src, pal1);
    pull1_k<<<(N + 3) / 4, 256, 0, stream>>>(off, cntt, src, pal1, h1b, s1, d1v, b1, agg1b, N);

    // ---- layer 2 ----
    gemm2_mfma<<<gblk, 256, 0, stream>>>(agg1b, w2t, as2, ad2, h2b, s2, d2v, N);
    place2pal_k<<<eb2, 256, 0, stream>>>(ei2, E2, N, E1, cnt8, rnk, s2, d2v, src, pal2);
    pull2_k<<<(N + 3) / 4, 256, 0, stream>>>(off, cntt, src + E1, pal2, h2b, s2, d2v, b2, out, N, E1);
}

// Round 15
// 242.848 us; speedup vs baseline: 1.1219x; 1.0891x over previous
//
#include <hip/hip_runtime.h>

#define LRELU(v) ((v) > 0.f ? (v) : 0.2f * (v))

typedef __attribute__((ext_vector_type(8))) short bf16x8;
typedef __attribute__((ext_vector_type(4))) float f32x4;

__device__ __forceinline__ ushort f2bf(float x) {
    union { float f; unsigned u; } v; v.f = x;
    return (ushort)((v.u + 0x7FFF + ((v.u >> 16) & 1)) >> 16);   // RNE
}
__device__ __forceinline__ float bf2f(ushort b) {
    union { float f; unsigned u; } v; v.u = ((unsigned)b) << 16;
    return v.f;
}

// ---------------- weight transpose-cast: src[K][N] f32 -> dst[N][K] bf16 ----------------

__global__ void tcast_k(const float* __restrict__ src, ushort* __restrict__ dst, int K, int N) {
    int i = blockIdx.x * blockDim.x + threadIdx.x;
    if (i >= K * N) return;
    int k = i / N, c = i - k * N;
    dst[c * K + k] = f2bf(src[i]);
}

// ---------------- MFMA GEMM1: h1[M,256] = f2bf(x[M,128]) @ W1, + attn dots ----------------
// w1t [256][128] bf16 staged in LDS (64KB), XOR-swizzled 16B chunks: col' = col ^ (row&7).

__global__ __launch_bounds__(256) void gemm1_mfma(
        const float* __restrict__ x, const ushort* __restrict__ w1t,
        const float* __restrict__ asrc, const float* __restrict__ adst,
        ushort* __restrict__ hb, float* __restrict__ os, float* __restrict__ od, int M) {
    __shared__ ushort wl[32768];                     // 256 rows x 16 chunks x 8 ushorts
    const int tid = threadIdx.x;
#pragma unroll
    for (int it = 0; it < 16; ++it) {
        const int id = it * 256 + tid;               // chunk id
        const int row = id >> 4, col = id & 15;
        bf16x8 v = *(const bf16x8*)(w1t + (size_t)id * 8);
        *(bf16x8*)(wl + (((row << 4) | (col ^ (row & 7))) * 8)) = v;
    }
    __syncthreads();

    const int lane = tid & 63;
    const int c15 = lane & 15, rgrp = lane >> 4;
    const int row0 = blockIdx.x * 64 + (tid >> 6) * 16;
    int arow = row0 + c15; if (arow >= M) arow = M - 1;   // clamp: input buffer is exact-size

    bf16x8 a[4];
#pragma unroll
    for (int ks = 0; ks < 4; ++ks) {
        const float* ap = x + (size_t)arow * 128 + ks * 32 + rgrp * 8;
        const float4 f0 = *(const float4*)ap;
        const float4 f1 = *(const float4*)(ap + 4);
        bf16x8 t;
        t[0] = (short)f2bf(f0.x); t[1] = (short)f2bf(f0.y);
        t[2] = (short)f2bf(f0.z); t[3] = (short)f2bf(f0.w);
        t[4] = (short)f2bf(f1.x); t[5] = (short)f2bf(f1.y);
        t[6] = (short)f2bf(f1.z); t[7] = (short)f2bf(f1.w);
        a[ks] = t;
    }

    f32x4 acc[16];
#pragma unroll
    for (int ct = 0; ct < 16; ++ct) acc[ct] = (f32x4){0.f, 0.f, 0.f, 0.f};

#pragma unroll
    for (int ct = 0; ct < 16; ++ct) {
        const int r = ct * 16 + c15;
#pragma unroll
        for (int ks = 0; ks < 4; ++ks) {
            const int chunk = (r << 4) | ((ks * 4 + rgrp) ^ (r & 7));
            bf16x8 b = *(const bf16x8*)(wl + chunk * 8);
            acc[ct] = __builtin_amdgcn_mfma_f32_16x16x32_bf16(a[ks], b, acc[ct], 0, 0, 0);
        }
    }

#pragma unroll
    for (int ct = 0; ct < 16; ++ct) {
        const int col = ct * 16 + c15;
#pragma unroll
        for (int r = 0; r < 4; ++r) {
            const int row = row0 + rgrp * 4 + r;
            if (row < M) hb[(size_t)row * 256 + col] = f2bf(acc[ct][r]);
        }
    }

#pragma unroll
    for (int hd = 0; hd < 4; ++hd) {
        float sv[4] = {0.f, 0.f, 0.f, 0.f}, dv[4] = {0.f, 0.f, 0.f, 0.f};
#pragma unroll
        for (int j = 0; j < 4; ++j) {
            const int ct = hd * 4 + j;
            const float ws = asrc[ct * 16 + c15], wd = adst[ct * 16 + c15];
#pragma unroll
            for (int r = 0; r < 4; ++r) { sv[r] += acc[ct][r] * ws; dv[r] += acc[ct][r] * wd; }
        }
#pragma unroll
        for (int r = 0; r < 4; ++r) {
#pragma unroll
            for (int m = 1; m < 16; m <<= 1) {
                sv[r] += __shfl_xor(sv[r], m); dv[r] += __shfl_xor(dv[r], m);
            }
        }
        if (c15 == 0) {
#pragma unroll
            for (int r = 0; r < 4; ++r) {
                const int row = row0 + rgrp * 4 + r;
                if (row < M) { os[row * 4 + hd] = sv[r]; od[row * 4 + hd] = dv[r]; }
            }
        }
    }
}

// ---------------- MFMA GEMM2: h2[M,64] = aggb[M,256] @ W2, + attn dots ----------------
// w2t [64][256] bf16 staged in LDS (32KB), same chunk swizzle (32 chunks/row).

__global__ __launch_bounds__(256) void gemm2_mfma(
        const ushort* __restrict__ ab, const ushort* __restrict__ w2t,
        const float* __restrict__ asrc, const float* __restrict__ adst,
        ushort* __restrict__ hb, float* __restrict__ os, float* __restrict__ od, int M) {
    __shared__ ushort wl[16384];                     // 64 rows x 32 chunks x 8 ushorts
    const int tid = threadIdx.x;
#pragma unroll
    for (int it = 0; it < 8; ++it) {
        const int id = it * 256 + tid;               // chunk id
        const int row = id >> 5, col = id & 31;
        bf16x8 v = *(const bf16x8*)(w2t + (size_t)id * 8);
        *(bf16x8*)(wl + (((row << 5) | (col ^ (row & 7))) * 8)) = v;
    }
    __syncthreads();

    const int lane = tid & 63;
    const int c15 = lane & 15, rgrp = lane >> 4;
    const int row0 = blockIdx.x * 64 + (tid >> 6) * 16;

    bf16x8 a[8];
#pragma unroll
    for (int ks = 0; ks < 8; ++ks)
        a[ks] = *(const bf16x8*)(ab + (size_t)(row0 + c15) * 256 + ks * 32 + rgrp * 8);

    f32x4 acc[4];
#pragma unroll
    for (int ct = 0; ct < 4; ++ct) acc[ct] = (f32x4){0.f, 0.f, 0.f, 0.f};

#pragma unroll
    for (int ct = 0; ct < 4; ++ct) {
        const int r = ct * 16 + c15;
#pragma unroll
        for (int ks = 0; ks < 8; ++ks) {
            const int chunk = (r << 5) | ((ks * 4 + rgrp) ^ (r & 7));
            bf16x8 b = *(const bf16x8*)(wl + chunk * 8);
            acc[ct] = __builtin_amdgcn_mfma_f32_16x16x32_bf16(a[ks], b, acc[ct], 0, 0, 0);
        }
    }

#pragma unroll
    for (int ct = 0; ct < 4; ++ct) {
        const int col = ct * 16 + c15;
#pragma unroll
        for (int r = 0; r < 4; ++r) {
            const int row = row0 + rgrp * 4 + r;
            if (row < M) hb[(size_t)row * 64 + col] = f2bf(acc[ct][r]);
        }
    }

    float sv[4] = {0.f, 0.f, 0.f, 0.f}, dv[4] = {0.f, 0.f, 0.f, 0.f};
#pragma unroll
    for (int ct = 0; ct < 4; ++ct) {
        const float ws = asrc[ct * 16 + c15], wd = adst[ct * 16 + c15];
#pragma unroll
        for (int r = 0; r < 4; ++r) { sv[r] += acc[ct][r] * ws; dv[r] += acc[ct][r] * wd; }
    }
#pragma unroll
    for (int r = 0; r < 4; ++r) {
#pragma unroll
        for (int m = 1; m < 16; m <<= 1) {
            sv[r] += __shfl_xor(sv[r], m); dv[r] += __shfl_xor(dv[r], m);
        }
    }
    if (c15 == 0) {
#pragma unroll
        for (int r = 0; r < 4; ++r) {
            const int row = row0 + rgrp * 4 + r;
            if (row < M) { os[row] = sv[r]; od[row] = dv[r]; }
        }
    }
}

// ---------------- CSR build: rank (standalone, low-VGPR) / scan / place ----------------
// replica plane = (t>>10)&7, consistent between rank and place.

__global__ void rank_all_k(const int* __restrict__ ei1, int E1,
                           const int* __restrict__ ei2, int E2, int N,
                           int* __restrict__ cnt8, int* __restrict__ rnk) {
    const int base = blockIdx.x * 1024;
    int* __restrict__ c = cnt8 + (size_t)(blockIdx.x & 7) * 2 * N;
#pragma unroll
    for (int j = 0; j < 4; ++j) {
        const int t = base + j * 256 + threadIdx.x;
        if (t < E1)            rnk[t] = atomicAdd(&c[ei1[E1 + t]], 1);
        else if (t < E1 + E2)  rnk[t] = atomicAdd(&c[N + ei2[E2 + (t - E1)]], 1);
    }
}

__global__ void scan1_k(const int* __restrict__ cnt8, int* __restrict__ cnt_tot,
                        int* __restrict__ off, int* __restrict__ bsum, int NN) {
    __shared__ int tmp[256];
    const int i = blockIdx.x * 256 + threadIdx.x;
    int v = 0;
    if (i < NN) {
#pragma unroll
        for (int r = 0; r < 8; ++r) v += cnt8[(size_t)r * NN + i];
        cnt_tot[i] = v;
    }
    tmp[threadIdx.x] = v;
    __syncthreads();
#pragma unroll
    for (int d = 1; d < 256; d <<= 1) {
        int t = (threadIdx.x >= d) ? tmp[threadIdx.x - d] : 0;
        __syncthreads();
        tmp[threadIdx.x] += t;
        __syncthreads();
    }
    if (i < NN) off[i] = tmp[threadIdx.x] - v;
    if (threadIdx.x == 255) bsum[blockIdx.x] = tmp[255];
}

__global__ void scan23_k(int* __restrict__ off, const int* __restrict__ bsum,
                         int* __restrict__ cnt8, int NN) {
    const int b = blockIdx.x;
    int pre = 0;
    for (int i = (threadIdx.x & 63); i < b; i += 64) pre += bsum[i];
#pragma unroll
    for (int m = 1; m < 64; m <<= 1) pre += __shfl_xor(pre, m);
    const int i = b * 256 + threadIdx.x;
    if (i < NN) {
        int run = off[i] + pre;
        off[i] = run;
#pragma unroll
        for (int r = 0; r < 8; ++r) {
            const int c = cnt8[(size_t)r * NN + i];
            cnt8[(size_t)r * NN + i] = run;
            run += c;
        }
    }
}

__global__ void place_all_k(const int* __restrict__ ei1, int E1,
                            const int* __restrict__ ei2, int E2, int N,
                            const int* __restrict__ base8, const int* __restrict__ rnk,
                            int2* __restrict__ edg) {
    const int base = blockIdx.x * 1024;
#pragma unroll
    for (int j = 0; j < 4; ++j) {
        const int t = base + j * 256 + threadIdx.x;
        const int* __restrict__ bp = base8 + (size_t)((t >> 10) & 7) * 2 * N;
        if (t < E1) {
            const int s = ei1[t], d = ei1[E1 + t];
            edg[bp[d] + rnk[t]] = make_int2(s, d);
        } else if (t < E1 + E2) {
            const int e = t - E1;
            const int s = ei2[e], d = ei2[E2 + e];
            edg[bp[N + d] + rnk[t]] = make_int2(s, d);
        }
    }
}

// ---------------- alpha precompute (CSR slot order) ----------------

__global__ void palpha1_k(const int2* __restrict__ edg, int E,
                          const float* __restrict__ as, const float* __restrict__ ad,
                          float* __restrict__ pal) {
    int i = blockIdx.x * blockDim.x + threadIdx.x;
    if (i >= E) return;
    const int2 e = edg[i];
    const float4 av = *(const float4*)(as + (size_t)e.x * 4);
    const float4 dv = *(const float4*)(ad + (size_t)e.y * 4);
    float4 p;
    p.x = __expf(LRELU(av.x + dv.x));
    p.y = __expf(LRELU(av.y + dv.y));
    p.z = __expf(LRELU(av.z + dv.z));
    p.w = __expf(LRELU(av.w + dv.w));
    ((float4*)pal)[i] = p;
}

__global__ void palpha2_k(const int2* __restrict__ edg, int E,
                          const float* __restrict__ as, const float* __restrict__ ad,
                          float* __restrict__ pal) {
    int i = blockIdx.x * blockDim.x + threadIdx.x;
    if (i >= E) return;
    const int2 e = edg[i];
    pal[i] = __expf(LRELU(as[e.x] + ad[e.y]));
}

// ---------------- pull aggregation ----------------

// layer 1: one wave per node; 8-edge unrolled gathers
__global__ __launch_bounds__(256) void pull1_k(
        const int* __restrict__ off, const int* __restrict__ cnt,
        const int2* __restrict__ edg, const float* __restrict__ pal,
        const ushort* __restrict__ hb,
        const float* __restrict__ as, const float* __restrict__ ad,
        const float* __restrict__ bias, ushort* __restrict__ aggb, int N) {
    const int n = blockIdx.x * 4 + (threadIdx.x >> 6);
    if (n >= N) return;
    const int lane = threadIdx.x & 63;
    const int hh = lane >> 4;
    const int start = off[n];
    const int end = start + cnt[n];
    float4 acc = {0.f, 0.f, 0.f, 0.f};
    float den = 0.f;
    int i = start;
    for (; i + 8 <= end; i += 8) {
        int ss[8]; float pp[8]; ushort4 hv[8];
#pragma unroll
        for (int j = 0; j < 8; ++j) {
            ss[j] = edg[i + j].x;
            pp[j] = pal[(size_t)(i + j) * 4 + hh];
        }
#pragma unroll
        for (int j = 0; j < 8; ++j)
            hv[j] = *(const ushort4*)(hb + (size_t)ss[j] * 256 + lane * 4);
#pragma unroll
        for (int j = 0; j < 8; ++j) {
            den += pp[j];
            acc.x += pp[j] * bf2f(hv[j].x); acc.y += pp[j] * bf2f(hv[j].y);
            acc.z += pp[j] * bf2f(hv[j].z); acc.w += pp[j] * bf2f(hv[j].w);
        }
    }
    for (; i + 4 <= end; i += 4) {
        int ss[4]; float pp[4]; ushort4 hv[4];
#pragma unroll
        for (int j = 0; j < 4; ++j) {
            ss[j] = edg[i + j].x;
            pp[j] = pal[(size_t)(i + j) * 4 + hh];
        }
#pragma unroll
        for (int j = 0; j < 4; ++j)
            hv[j] = *(const ushort4*)(hb + (size_t)ss[j] * 256 + lane * 4);
#pragma unroll
        for (int j = 0; j < 4; ++j) {
            den += pp[j];
            acc.x += pp[j] * bf2f(hv[j].x); acc.y += pp[j] * bf2f(hv[j].y);
            acc.z += pp[j] * bf2f(hv[j].z); acc.w += pp[j] * bf2f(hv[j].w);
        }
    }
    for (; i < end; ++i) {
        const int s = edg[i].x;
        const float p = pal[(size_t)i * 4 + hh];
        const ushort4 hv = *(const ushort4*)(hb + (size_t)s * 256 + lane * 4);
        den += p;
        acc.x += p * bf2f(hv.x); acc.y += p * bf2f(hv.y);
        acc.z += p * bf2f(hv.z); acc.w += p * bf2f(hv.w);
    }
    {   // self-loop
        const float p = __expf(LRELU(as[n * 4 + hh] + ad[n * 4 + hh]));
        const ushort4 hv = *(const ushort4*)(hb + (size_t)n * 256 + lane * 4);
        den += p;
        acc.x += p * bf2f(hv.x); acc.y += p * bf2f(hv.y);
        acc.z += p * bf2f(hv.z); acc.w += p * bf2f(hv.w);
    }
    const float rden = 1.f / den;
    const float4 bv = *(const float4*)(bias + lane * 4);
    ushort4 o;
    o.x = f2bf(fmaxf(acc.x * rden + bv.x, 0.f));
    o.y = f2bf(fmaxf(acc.y * rden + bv.y, 0.f));
    o.z = f2bf(fmaxf(acc.z * rden + bv.z, 0.f));
    o.w = f2bf(fmaxf(acc.w * rden + bv.w, 0.f));
    *(ushort4*)(aggb + (size_t)n * 256 + lane * 4) = o;
}

// layer 2: one wave per node, 8 edges/iter (2 groups in flight); fused bias + L2 norm
__global__ __launch_bounds__(256) void pull2_k(
        const int* __restrict__ off, const int* __restrict__ cnt,
        const int2* __restrict__ edg, const float* __restrict__ pal,
        const ushort* __restrict__ hb,
        const float* __restrict__ as, const float* __restrict__ ad,
        const float* __restrict__ bias, float* __restrict__ out, int N, int E1) {
    const int n = blockIdx.x * 4 + (threadIdx.x >> 6);
    if (n >= N) return;
    const int lane = threadIdx.x & 63;
    const int g = lane >> 4;
    const int q = lane & 15;
    const int start = off[N + n] - E1;   // local slot within layer-2 region
    const int end = start + cnt[N + n];
    float4 acc = {0.f, 0.f, 0.f, 0.f};
    float den = 0.f;
    int base = start;
    for (; base + 8 <= end; base += 8) {
        const int i0 = base + g, i1 = base + 4 + g;
        const int s0 = edg[i0].x, s1 = edg[i1].x;
        const float p0 = pal[i0], p1 = pal[i1];
        const ushort4 h0 = *(const ushort4*)(hb + (size_t)s0 * 64 + q * 4);
        const ushort4 h1 = *(const ushort4*)(hb + (size_t)s1 * 64 + q * 4);
        den += p0 + p1;
        acc.x += p0 * bf2f(h0.x) + p1 * bf2f(h1.x);
        acc.y += p0 * bf2f(h0.y) + p1 * bf2f(h1.y);
        acc.z += p0 * bf2f(h0.z) + p1 * bf2f(h1.z);
        acc.w += p0 * bf2f(h0.w) + p1 * bf2f(h1.w);
    }
    for (; base < end; base += 4) {
        const int idx = base + g;
        const bool valid = idx < end;
        const int s = valid ? edg[idx].x : n;
        const float p = valid ? pal[idx] : 0.f;
        const ushort4 hv = *(const ushort4*)(hb + (size_t)s * 64 + q * 4);
        den += p;
        acc.x += p * bf2f(hv.x); acc.y += p * bf2f(hv.y);
        acc.z += p * bf2f(hv.z); acc.w += p * bf2f(hv.w);
    }
    if (g == 0) {   // self-loop counted once
        const float p = __expf(LRELU(as[n] + ad[n]));
        const ushort4 hv = *(const ushort4*)(hb + (size_t)n * 64 + q * 4);
        den += p;
        acc.x += p * bf2f(hv.x); acc.y += p * bf2f(hv.y);
        acc.z += p * bf2f(hv.z); acc.w += p * bf2f(hv.w);
    }
#pragma unroll
    for (int m = 16; m < 64; m <<= 1) {
        acc.x += __shfl_xor(acc.x, m); acc.y += __shfl_xor(acc.y, m);
        acc.z += __shfl_xor(acc.z, m); acc.w += __shfl_xor(acc.w, m);
        den   += __shfl_xor(den, m);
    }
    const float rden = 1.f / den;
    const float4 bv = *(const float4*)(bias + q * 4);
    float4 v;
    v.x = acc.x * rden + bv.x; v.y = acc.y * rden + bv.y;
    v.z = acc.z * rden + bv.z; v.w = acc.w * rden + bv.w;
    float ss = v.x * v.x + v.y * v.y + v.z * v.z + v.w * v.w;
#pragma unroll
    for (int m = 1; m < 16; m <<= 1) ss += __shfl_xor(ss, m);
    const float rn = 1.f / fmaxf(sqrtf(ss), 1e-12f);
    if (g == 0) {
        float4 o; o.x = v.x * rn; o.y = v.y * rn; o.z = v.z * rn; o.w = v.w * rn;
        *(float4*)(out + (size_t)n * 64 + q * 4) = o;
    }
}

// ---------------- launch ----------------

extern "C" void kernel_launch(void* const* d_in, const int* in_sizes, int n_in,
                              void* d_out, int out_size, void* d_ws, size_t ws_size,
                              hipStream_t stream) {
    const float* x   = (const float*)d_in[0];
    const int*   ei1 = (const int*)d_in[1];
    const int*   ei2 = (const int*)d_in[2];
    const float* W1  = (const float*)d_in[3];
    const float* as1 = (const float*)d_in[4];
    const float* ad1 = (const float*)d_in[5];
    const float* b1  = (const float*)d_in[6];
    const float* W2  = (const float*)d_in[7];
    const float* as2 = (const float*)d_in[8];
    const float* ad2 = (const float*)d_in[9];
    const float* b2  = (const float*)d_in[10];

    const int N  = in_sizes[0] / 128;
    const int E1 = in_sizes[1] / 2;
    const int E2 = in_sizes[2] / 2;
    const int Etot = E1 + E2;
    const int NN = 2 * N;

    // ws layout (~94 MB)
    ushort* h1b   = (ushort*)d_ws;                      // N*256 bf16
    ushort* agg1b = h1b + (size_t)N * 256;              // N*256 bf16
    ushort* h2b   = agg1b + (size_t)N * 256;            // N*64  bf16
    ushort* w1t   = h2b + (size_t)N * 64;               // 256*128
    ushort* w2t   = w1t + 256 * 128;                    // 64*256
    float*  pal1  = (float*)(w2t + 64 * 256);           // E1*4 floats
    int*    rnk   = (int*)pal1;                         // Etot ints (dead before pal1 written)
    float*  pal2  = pal1 + (size_t)E1 * 4;              // E2 floats
    int2*   edg   = (int2*)(pal2 + E2);                 // Etot int2
    int*    cnt8  = (int*)(edg + Etot);                 // 8 * 2N (becomes base8)
    int*    off   = cnt8 + (size_t)8 * NN;              // 2N
    int*    cntt  = off + NN;                           // 2N
    int*    bsum  = cntt + NN;                          // 512
    float*  s1    = (float*)(bsum + 512);               // N*4
    float*  d1v   = s1 + (size_t)N * 4;                 // N*4
    float*  s2    = d1v + (size_t)N * 4;                // N
    float*  d2v   = s2 + N;                             // N
    float*  out   = (float*)d_out;

    const int nb  = (NN + 255) / 256;
    const int eb4 = (Etot + 1023) / 1024;   // 4 edges/thread
    const int gblk = (N + 63) / 64;

    // prep
    tcast_k<<<(128 * 256 + 255) / 256, 256, 0, stream>>>(W1, w1t, 128, 256);
    tcast_k<<<(256 * 64 + 255) / 256, 256, 0, stream>>>(W2, w2t, 256, 64);
    hipMemsetAsync(cnt8, 0, (size_t)8 * NN * sizeof(int), stream);

    // CSR build
    rank_all_k<<<eb4, 256, 0, stream>>>(ei1, E1, ei2, E2, N, cnt8, rnk);
    scan1_k<<<nb, 256, 0, stream>>>(cnt8, cntt, off, bsum, NN);
    scan23_k<<<nb, 256, 0, stream>>>(off, bsum, cnt8, NN);
    place_all_k<<<eb4, 256, 0, stream>>>(ei1, E1, ei2, E2, N, cnt8, rnk, edg);

    // ---- layer 1 ----
    gemm1_mfma<<<gblk, 256, 0, stream>>>(x, w1t, as1, ad1, h1b, s1, d1v, N);
    palpha1_k<<<(E1 + 255) / 256, 256, 0, stream>>>(edg, E1, s1, d1v, pal1);
    pull1_k<<<(N + 3) / 4, 256, 0, stream>>>(off, cntt, edg, pal1, h1b, s1, d1v, b1, agg1b, N);

    // ---- layer 2 ----
    gemm2_mfma<<<gblk, 256, 0, stream>>>(agg1b, w2t, as2, ad2, h2b, s2, d2v, N);
    palpha2_k<<<(E2 + 255) / 256, 256, 0, stream>>>(edg + E1, E2, s2, d2v, pal2);
    pull2_k<<<(N + 3) / 4, 256, 0, stream>>>(off, cntt, edg + E1, pal2, h2b, s2, d2v, b2, out, N, E1);
}